// Round 10
// baseline (102.438 us; speedup 1.0000x reference)
//
#include <hip/hip_runtime.h>
#include <hip/hip_bf16.h>
#include <math.h>

#define N_PIX 4096
#define CCH 32
#define BB 2
#define PIX_P 4356   // 66*66 padded pixel grid

typedef __attribute__((ext_vector_type(8))) short short8;
typedef __attribute__((ext_vector_type(4))) float f32x4;
typedef __attribute__((ext_vector_type(16))) float f32x16;

// ---------------------------------------------------------------------------
// Weight convert/reorder: fp32 [co][cin][3][3] -> bf16 [co][kk][ci]
// ---------------------------------------------------------------------------
struct WcvtPar {
  const float* src[11];
  int cin[11];
  int dst[11];     // element offset into wbf arena
};

__global__ __launch_bounds__(256) void wcvt_k(WcvtPar p, __hip_bfloat16* __restrict__ wbf)
{
  const int s = blockIdx.y;
  const int cin = p.cin[s];
  const int K = 9*cin;
  const int total = 32*K;
  const float* __restrict__ src = p.src[s];
  __hip_bfloat16* __restrict__ dst = wbf + p.dst[s];
  for (int j = blockIdx.x*256 + threadIdx.x; j < total; j += gridDim.x*256) {
    int co = j / K, k = j - co*K;
    int kk = k / cin, ci = k - kk*cin;
    dst[j] = __float2bfloat16(src[(size_t)(co*cin + ci)*9 + kk]);
  }
}

// ---------------------------------------------------------------------------
// Border-zero: zero the 260 border pixels of each padded slot.
// ---------------------------------------------------------------------------
struct BzPar { __hip_bfloat16* p[16]; int sch[16]; };

__global__ __launch_bounds__(256) void bzero_k(BzPar bp)
{
  const int s = blockIdx.x;
  const int sch = bp.sch[s];
  __hip_bfloat16* __restrict__ ptr = bp.p[s];
  const int total = 260*sch;
  for (int j = threadIdx.x; j < total; j += 256) {
    int e = j / sch, c = j - e*sch;
    int yy, xx;
    if (e < 66)       { yy = 0;       xx = e; }
    else if (e < 132) { yy = 65;      xx = e - 66; }
    else if (e < 196) { yy = e - 131; xx = 0; }     // rows 1..64
    else              { yy = e - 195; xx = 65; }
    ptr[((size_t)yy*66 + xx)*sch + c] = __float2bfloat16(0.f);
  }
}

// ---------------------------------------------------------------------------
// x fp32 NCHW -> bf16 padded pixel-major xcat[b][66*66][96], channels 0..63.
// ---------------------------------------------------------------------------
__global__ __launch_bounds__(256) void xpad_k(const float* __restrict__ x,
                                              __hip_bfloat16* __restrict__ xcat)
{
  const int y = blockIdx.x, b = blockIdx.y;
  const int t = threadIdx.x;
  for (int j = t; j < 4096; j += 256) {
    int ci = j >> 6, xx = j & 63;
    float v = x[((size_t)(b*64 + ci)*64 + y)*64 + xx];
    xcat[((size_t)b*PIX_P + (size_t)(y+1)*66 + xx+1)*96 + ci] = __float2bfloat16(v);
  }
}

// ---------------------------------------------------------------------------
// avg3: ctx = (r+g+b)/3 -> xcat channels 64..95 (padded interior).
// ---------------------------------------------------------------------------
__global__ __launch_bounds__(256) void avg3_k(
    const __hip_bfloat16* __restrict__ r, const __hip_bfloat16* __restrict__ g,
    const __hip_bfloat16* __restrict__ bl, __hip_bfloat16* __restrict__ xcat)
{
  const int y = blockIdx.x, b = blockIdx.y;
  const int t = threadIdx.x;
  for (int j = t; j < 64*32; j += 256) {
    int xx = j >> 5, c = j & 31;
    size_t src = ((size_t)b*N_PIX + y*64 + xx)*32 + c;
    float v = (__bfloat162float(r[src]) + __bfloat162float(g[src]) +
               __bfloat162float(bl[src])) * (1.0f/3.0f);
    xcat[((size_t)b*PIX_P + (size_t)(y+1)*66 + xx+1)*96 + 64 + c] = __float2bfloat16(v);
  }
}

// ---------------------------------------------------------------------------
// MFMA implicit-GEMM 3x3 conv + bias + ReLU. K-SPLIT version:
// block = 256 thr = 4 waves; all waves cover the SAME 16 pixels, each wave a
// quarter of the K range; partials reduced through LDS; wave 0 stores.
// Raises occupancy: a1-a3 1.5 -> 6 waves/SIMD, a4/a5 1 -> 2 waves/SIMD.
// ---------------------------------------------------------------------------
struct ConvPar {
  const __hip_bfloat16* in[3];
  const __hip_bfloat16* wb[3];
  const float* bias[3];
  __hip_bfloat16* outPad[3];
  __hip_bfloat16* outPix[3];
  __hip_bfloat16* outCh[3];
  float* outF[3];
  int mode, sch;
};

template<int CIN>
__global__ __launch_bounds__(256) void conv_mfma(ConvPar p)
{
  constexpr int K = 9*CIN;
  constexpr int S = K/32;            // total k-steps
  constexpr int Q = S/4, R = S%4;
  constexpr int e0 = Q + (R>0 ? 1:0);
  constexpr int e1 = e0 + Q + (R>1 ? 1:0);
  constexpr int e2 = e1 + Q + (R>2 ? 1:0);
  const int sel = blockIdx.y, b = blockIdx.z;
  const int sch = p.sch;
  const __hip_bfloat16* __restrict__ in = p.in[sel] + (size_t)b*PIX_P*sch;
  const __hip_bfloat16* __restrict__ wb = p.wb[sel];
  const float* __restrict__ bias = p.bias[sel];
  const int t = threadIdx.x, wave = t >> 6, lane = t & 63;
  const int l15 = lane & 15, q4 = lane >> 4;
  const int y = blockIdx.x >> 2;
  const int xw = (blockIdx.x & 3)*16;

  __shared__ float red[3][16][33];

  f32x4 acc0 = {0.f,0.f,0.f,0.f}, acc1 = {0.f,0.f,0.f,0.f};

#define CONV_BODY(ks)                                                          \
  {                                                                            \
    const int kk  = ((ks)*32)/CIN;                                             \
    const int ci0 = ((ks)*32)%CIN + q4*8;                                      \
    const int dy = kk/3 - 1, dx = (kk%3) - 1;                                  \
    const short8 bw0 = *(const short8*)&wb[(size_t)l15*K      + (ks)*32 + q4*8]; \
    const short8 bw1 = *(const short8*)&wb[(size_t)(16+l15)*K + (ks)*32 + q4*8]; \
    const short8 av  = *(const short8*)&in[((size_t)(y+1+dy)*66 + xw + l15 + 1 + dx)*sch + ci0]; \
    acc0 = __builtin_amdgcn_mfma_f32_16x16x32_bf16(av, bw0, acc0, 0, 0, 0);    \
    acc1 = __builtin_amdgcn_mfma_f32_16x16x32_bf16(av, bw1, acc1, 0, 0, 0);    \
  }

  if (wave == 0) {
    #pragma unroll
    for (int ks = 0; ks < e0; ++ks) CONV_BODY(ks)
  } else if (wave == 1) {
    #pragma unroll
    for (int ks = e0; ks < e1; ++ks) CONV_BODY(ks)
  } else if (wave == 2) {
    #pragma unroll
    for (int ks = e1; ks < e2; ++ks) CONV_BODY(ks)
  } else {
    #pragma unroll
    for (int ks = e2; ks < S; ++ks) CONV_BODY(ks)
  }
#undef CONV_BODY

  if (wave > 0) {
    #pragma unroll
    for (int r = 0; r < 4; ++r) {
      red[wave-1][q4*4 + r][l15]      = acc0[r];
      red[wave-1][q4*4 + r][16 + l15] = acc1[r];
    }
  }
  __syncthreads();
  if (wave == 0) {
    const float bz0 = bias[l15], bz1 = bias[16 + l15];
    #pragma unroll
    for (int r = 0; r < 4; ++r) {
      const int px = q4*4 + r;
      const float v0 = fmaxf(acc0[r] + red[0][px][l15] + red[1][px][l15]
                             + red[2][px][l15] + bz0, 0.f);
      const float v1 = fmaxf(acc1[r] + red[0][px][16+l15] + red[1][px][16+l15]
                             + red[2][px][16+l15] + bz1, 0.f);
      const int xx = xw + px;
      const int pix = y*64 + xx;
      if (p.mode & 1) {
        __hip_bfloat16* o = p.outPad[sel] + ((size_t)b*PIX_P + (size_t)(y+1)*66 + xx+1)*32;
        o[l15] = __float2bfloat16(v0); o[16+l15] = __float2bfloat16(v1);
      }
      if (p.mode & 2) {
        __hip_bfloat16* o = p.outPix[sel] + ((size_t)b*N_PIX + pix)*32;
        o[l15] = __float2bfloat16(v0); o[16+l15] = __float2bfloat16(v1);
      }
      if (p.mode & 4) {
        __hip_bfloat16* o = p.outCh[sel] + (size_t)b*32*N_PIX + pix;
        o[(size_t)l15*N_PIX]      = __float2bfloat16(v0);
        o[(size_t)(16+l15)*N_PIX] = __float2bfloat16(v1);
      }
      if (p.mode & 8) {
        float* o = p.outF[sel] + (size_t)b*32*N_PIX + pix;
        o[(size_t)l15*N_PIX]      = v0;
        o[(size_t)(16+l15)*N_PIX] = v1;
      }
    }
  }
}

// ---------------------------------------------------------------------------
// Attention pass, 32x32x16 MFMA, in-register P (verified R8/R9).
// This round: bare v_exp_f32 (args bounded, no ocml range fixup needed) and
// #pragma unroll 2 on the m-loop for cross-tile ILP. VGPR capped for
// 6 waves/SIMD via launch_bounds.
// ---------------------------------------------------------------------------
__global__ __launch_bounds__(512, 6) void attn_mfma(
    const __hip_bfloat16* __restrict__ qP, const __hip_bfloat16* __restrict__ kP,
    const __hip_bfloat16* __restrict__ vP,
    const __hip_bfloat16* __restrict__ qC, const __hip_bfloat16* __restrict__ kC,
    const __hip_bfloat16* __restrict__ vC,
    __hip_bfloat16* __restrict__ ctxPad)
{
  const int pass = blockIdx.y, b = blockIdx.z;
  const __hip_bfloat16 *XT, *YT, *ZD;
  if (pass == 0)      { XT = qP; YT = kP; ZD = vC; }
  else if (pass == 1) { XT = kP; YT = vP; ZD = qC; }
  else                { XT = vP; YT = qP; ZD = kC; }
  const size_t boff = (size_t)b * CCH * N_PIX;
  XT += boff; YT += boff; ZD += boff;
  __hip_bfloat16* __restrict__ ctx = ctxPad + ((size_t)(pass*BB + b))*PIX_P*32;

  const int t = threadIdx.x;
  const int wave = t >> 6, lane = t & 63;
  const int l31 = lane & 31, l5 = lane >> 5;
  const int n0 = blockIdx.x * 32;
  const int mbase = wave * (N_PIX/8);

  __shared__ float mgO[7][16][64];   // waves 1..7 partial O
  __shared__ float mgD[8][32];       // per-wave denominators by query i

  // GEMM1 B-frag (X): col = i = lane&31, k = c = l5*8 + e (two K=16 halves)
  const short8 bx0 = *(const short8*)&XT[(size_t)(n0 + l31)*CCH + l5*8];
  const short8 bx1 = *(const short8*)&XT[(size_t)(n0 + l31)*CCH + 16 + l5*8];

  f32x16 oacc = {0,0,0,0,0,0,0,0,0,0,0,0,0,0,0,0};
  float rs0 = 0.f, rs1 = 0.f, rs2 = 0.f, rs3 = 0.f;
  const float SC2 = 0.17677669529663687f * 1.4426950408889634f;  // 32^-0.5 * log2(e)
  const float OFF = 20.0f;

  #pragma unroll 2
  for (int m0 = mbase; m0 < mbase + N_PIX/8; m0 += 32) {
    // GEMM1: A = Y rows (m = lane&31)
    const short8 ay0 = *(const short8*)&YT[(size_t)(m0 + l31)*CCH + l5*8];
    const short8 ay1 = *(const short8*)&YT[(size_t)(m0 + l31)*CCH + 16 + l5*8];
    f32x16 s = {0,0,0,0,0,0,0,0,0,0,0,0,0,0,0,0};
    s = __builtin_amdgcn_mfma_f32_32x32x16_bf16(ay0, bx0, s, 0, 0, 0);
    s = __builtin_amdgcn_mfma_f32_32x32x16_bf16(ay1, bx1, s, 0, 0, 0);

    // P = 2^(s*SC2 - OFF) via bare v_exp_f32 (args bounded; no range fixup)
    float p[16];
    #pragma unroll
    for (int r = 0; r < 16; ++r) {
      const float arg = fmaf(s[r], SC2, -OFF);
      asm("v_exp_f32 %0, %1" : "=v"(p[r]) : "v"(arg));
    }
    #pragma unroll
    for (int r = 0; r < 4; ++r) {
      rs0 += p[r];
      rs1 += p[4 + r];
      rs2 += p[8 + r];
      rs3 += p[12 + r];
    }

    // pack to bf16 pairs: w[rhi*2+j] = {m = 8*rhi + 4*l5 + 2j, +1}
    unsigned w[8];
    #pragma unroll
    for (int h = 0; h < 8; ++h) {
      const int rhi = h >> 1, j = h & 1;
      asm("v_cvt_pk_bf16_f32 %0, %1, %2"
          : "=v"(w[h]) : "v"(p[rhi*4 + 2*j]), "v"(p[rhi*4 + 2*j + 1]));
    }
    // lane<->lane+32 exchange -> GEMM2 A-fragments in-register
    asm("v_permlane32_swap_b32 %0, %1" : "+v"(w[2]), "+v"(w[0]));
    asm("v_permlane32_swap_b32 %0, %1" : "+v"(w[3]), "+v"(w[1]));
    asm("v_permlane32_swap_b32 %0, %1" : "+v"(w[6]), "+v"(w[4]));
    asm("v_permlane32_swap_b32 %0, %1" : "+v"(w[7]), "+v"(w[5]));
    union U { unsigned u[4]; short8 v8; };
    U A0, A1;
    A0.u[0] = w[0]; A0.u[1] = w[1]; A0.u[2] = w[2]; A0.u[3] = w[3];
    A1.u[0] = w[4]; A1.u[1] = w[5]; A1.u[2] = w[6]; A1.u[3] = w[7];

    // GEMM2: B = Z cols (c = lane&31, k = m-octet l5*8) from channel-major
    const short8 bz0 = *(const short8*)&ZD[(size_t)l31*N_PIX + m0 + l5*8];
    const short8 bz1 = *(const short8*)&ZD[(size_t)l31*N_PIX + m0 + 16 + l5*8];
    oacc = __builtin_amdgcn_mfma_f32_32x32x16_bf16(A0.v8, bz0, oacc, 0, 0, 0);
    oacc = __builtin_amdgcn_mfma_f32_32x32x16_bf16(A1.v8, bz1, oacc, 0, 0, 0);
  }

  // denominator: combine partials + l5 halves -> full sum for query i
  float rs = (rs0 + rs1) + (rs2 + rs3);
  rs += __shfl_xor(rs, 32);
  if (l5 == 0) mgD[wave][l31] = rs;
  if (wave) {
    #pragma unroll
    for (int r = 0; r < 16; ++r) mgO[wave-1][r][lane] = oacc[r];
  }
  __syncthreads();
  if (wave == 0) {
    #pragma unroll
    for (int r = 0; r < 16; ++r) {
      const int i = (r & 3) + 8*(r >> 2) + 4*l5;
      float den = 0.f, tot = oacc[r];
      #pragma unroll
      for (int ww = 0; ww < 8; ++ww) den += mgD[ww][i];
      #pragma unroll
      for (int ww = 0; ww < 7; ++ww) tot += mgO[ww][r][lane];
      const int pix = n0 + i;
      const int yy = pix >> 6, xx = pix & 63;
      ctx[((size_t)(yy+1)*66 + xx+1)*32 + l31] = __float2bfloat16(tot / den);
    }
  }
}

// ---------------------------------------------------------------------------
extern "C" void kernel_launch(void* const* d_in, const int* in_sizes, int n_in,
                              void* d_out, int out_size, void* d_ws, size_t ws_size,
                              hipStream_t stream)
{
  const float* x   = (const float*)d_in[0];
  const float* wq1 = (const float*)d_in[1];  const float* bq1 = (const float*)d_in[2];
  const float* wq2 = (const float*)d_in[3];  const float* bq2 = (const float*)d_in[4];
  const float* wk1 = (const float*)d_in[5];  const float* bk1 = (const float*)d_in[6];
  const float* wk2 = (const float*)d_in[7];  const float* bk2 = (const float*)d_in[8];
  const float* wv1 = (const float*)d_in[9];  const float* bv1 = (const float*)d_in[10];
  const float* wv2 = (const float*)d_in[11]; const float* bv2 = (const float*)d_in[12];
  const float* wr  = (const float*)d_in[13]; const float* br  = (const float*)d_in[14];
  const float* wg  = (const float*)d_in[15]; const float* bg  = (const float*)d_in[16];
  const float* wb_ = (const float*)d_in[17]; const float* bb_ = (const float*)d_in[18];
  const float* w2  = (const float*)d_in[19]; const float* b2  = (const float*)d_in[20];
  const float* w3  = (const float*)d_in[21]; const float* b3  = (const float*)d_in[22];

  // ---- workspace layout (bytes) ----
  char* base = (char*)d_ws;
  __hip_bfloat16* xcat  = (__hip_bfloat16*)(base + 0);        // [2][4356][96] padded
  __hip_bfloat16* q1p   = (__hip_bfloat16*)(base + 1672704);  // [3][2][4356][32] padded (later rgb)
  __hip_bfloat16* ctxP  = (__hip_bfloat16*)(base + 3345408);  // [3][2][4356][32] padded
  __hip_bfloat16* out4p = (__hip_bfloat16*)(base + 5018112);  // [2][4356][32] padded
  __hip_bfloat16* qkvP  = (__hip_bfloat16*)(base + 5575680);  // [3][2][4096][32]
  __hip_bfloat16* qkvC  = (__hip_bfloat16*)(base + 7148544);  // [3][2][32][4096]
  __hip_bfloat16* wbf   = (__hip_bfloat16*)(base + 8721408);  // 147456 elems
  const size_t PADSLOT = (size_t)BB*PIX_P*32;
  const size_t UPSLOT  = (size_t)BB*N_PIX*32;

  // border zeros for all padded slots (interiors fully overwritten per call)
  BzPar bz;
  for (int i = 0; i < 2; ++i)  { bz.p[i]      = xcat  + (size_t)i*PIX_P*96; bz.sch[i]      = 96; }
  for (int i = 0; i < 6; ++i)  { bz.p[2+i]    = q1p   + (size_t)i*PIX_P*32; bz.sch[2+i]    = 32; }
  for (int i = 0; i < 6; ++i)  { bz.p[8+i]    = ctxP  + (size_t)i*PIX_P*32; bz.sch[8+i]    = 32; }
  for (int i = 0; i < 2; ++i)  { bz.p[14+i]   = out4p + (size_t)i*PIX_P*32; bz.sch[14+i]   = 32; }
  bzero_k<<<dim3(16), dim3(256), 0, stream>>>(bz);

  // weight convert/reorder + x padding
  WcvtPar wp;
  const float* wsrc[11] = {wq1,wk1,wv1,wq2,wk2,wv2,wr,wg,wb_,w2,w3};
  const int    wcin[11] = {64,64,64,32,32,32,32,32,32,96,32};
  const int    wdst[11] = {0,18432,36864,55296,64512,73728,82944,92160,101376,110592,138240};
  for (int i = 0; i < 11; ++i) { wp.src[i]=wsrc[i]; wp.cin[i]=wcin[i]; wp.dst[i]=wdst[i]; }
  wcvt_k<<<dim3(54, 11), dim3(256), 0, stream>>>(wp, wbf);
  xpad_k<<<dim3(64, BB), dim3(256), 0, stream>>>(x, xcat);

  // a1: xcat(ch 0..63) -> q1p/k1p/v1p (padded bf16)
  ConvPar c1 = {};
  for (int i = 0; i < 3; ++i) c1.in[i] = xcat;
  c1.wb[0]=wbf+0; c1.wb[1]=wbf+18432; c1.wb[2]=wbf+36864;
  c1.bias[0]=bq1; c1.bias[1]=bk1; c1.bias[2]=bv1;
  c1.outPad[0]=q1p; c1.outPad[1]=q1p+PADSLOT; c1.outPad[2]=q1p+2*PADSLOT;
  c1.mode = 1; c1.sch = 96;
  conv_mfma<64><<<dim3(256, 3, BB), dim3(256), 0, stream>>>(c1);

  // a2: q1p -> q/k/v in BOTH layouts
  ConvPar c2 = {};
  c2.in[0]=q1p; c2.in[1]=q1p+PADSLOT; c2.in[2]=q1p+2*PADSLOT;
  c2.wb[0]=wbf+55296; c2.wb[1]=wbf+64512; c2.wb[2]=wbf+73728;
  c2.bias[0]=bq2; c2.bias[1]=bk2; c2.bias[2]=bv2;
  c2.outPix[0]=qkvP; c2.outPix[1]=qkvP+UPSLOT; c2.outPix[2]=qkvP+2*UPSLOT;
  c2.outCh[0]=qkvC;  c2.outCh[1]=qkvC+UPSLOT;  c2.outCh[2]=qkvC+2*UPSLOT;
  c2.mode = 6; c2.sch = 32;
  conv_mfma<32><<<dim3(256, 3, BB), dim3(256), 0, stream>>>(c2);

  // attention: 3 passes x 2 batches -> ctxP (padded bf16)
  attn_mfma<<<dim3(N_PIX/32, 3, BB), dim3(512), 0, stream>>>(
      qkvP, qkvP+UPSLOT, qkvP+2*UPSLOT, qkvC, qkvC+UPSLOT, qkvC+2*UPSLOT, ctxP);

  // a3: ctxP -> r/g/b (unpadded bf16 pixel-major, overlaid on q1p region)
  __hip_bfloat16* rgb = q1p;
  ConvPar c3 = {};
  c3.in[0]=ctxP; c3.in[1]=ctxP+PADSLOT; c3.in[2]=ctxP+2*PADSLOT;
  c3.wb[0]=wbf+82944; c3.wb[1]=wbf+92160; c3.wb[2]=wbf+101376;
  c3.bias[0]=br; c3.bias[1]=bg; c3.bias[2]=bb_;
  c3.outPix[0]=rgb; c3.outPix[1]=rgb+UPSLOT; c3.outPix[2]=rgb+2*UPSLOT;
  c3.mode = 2; c3.sch = 32;
  conv_mfma<32><<<dim3(256, 3, BB), dim3(256), 0, stream>>>(c3);

  // ctx average -> xcat channels 64..95
  avg3_k<<<dim3(64, BB), dim3(256), 0, stream>>>(rgb, rgb+UPSLOT, rgb+2*UPSLOT, xcat);

  // a4: xcat (96 ch) -> out4p (padded bf16)
  ConvPar c4 = {};
  c4.in[0]=xcat; c4.wb[0]=wbf+110592; c4.bias[0]=b2;
  c4.outPad[0]=out4p; c4.mode = 1; c4.sch = 96;
  conv_mfma<96><<<dim3(256, 1, BB), dim3(256), 0, stream>>>(c4);

  // a5: out4p -> d_out (fp32 NCHW)
  ConvPar c5 = {};
  c5.in[0]=out4p; c5.wb[0]=wbf+138240; c5.bias[0]=b3;
  c5.outF[0]=(float*)d_out; c5.mode = 8; c5.sch = 32;
  conv_mfma<32><<<dim3(256, 1, BB), dim3(256), 0, stream>>>(c5);
}

// Round 11
// 73.877 us; speedup vs baseline: 1.3866x; 1.3866x over previous
//
#include <hip/hip_runtime.h>
#include <hip/hip_bf16.h>
#include <math.h>

#define N_PIX 4096
#define CCH 32
#define BB 2
#define PIX_P 4356   // 66*66 padded pixel grid

typedef __attribute__((ext_vector_type(8))) short short8;
typedef __attribute__((ext_vector_type(4))) float f32x4;
typedef __attribute__((ext_vector_type(16))) float f32x16;

// ---------------------------------------------------------------------------
// prep_k: fused border-zero (blocks 0..15) + weight cvt/reorder (16..79) +
// x padding (80..207). One launch replaces three.
// Weight reorder: fp32 [co][cin][3][3] -> bf16 [co][kk][ci], flat arena.
// ---------------------------------------------------------------------------
struct PrepPar {
  __hip_bfloat16* bz[16]; int bzsch[16];
  const float* wsrc[11];
  const float* x;
  __hip_bfloat16* xcat;
  __hip_bfloat16* wbf;
};

__global__ __launch_bounds__(256) void prep_k(PrepPar p)
{
  const int blk = blockIdx.x, t = threadIdx.x;
  if (blk < 16) {
    const int sch = p.bzsch[blk];
    __hip_bfloat16* __restrict__ ptr = p.bz[blk];
    const int total = 260*sch;
    for (int j = t; j < total; j += 256) {
      int e = j / sch, c = j - e*sch;
      int yy, xx;
      if (e < 66)       { yy = 0;       xx = e; }
      else if (e < 132) { yy = 65;      xx = e - 66; }
      else if (e < 196) { yy = e - 131; xx = 0; }     // rows 1..64
      else              { yy = e - 195; xx = 65; }
      ptr[((size_t)yy*66 + xx)*sch + c] = __float2bfloat16(0.f);
    }
  } else if (blk < 80) {
    const int csum[12] = {0,18432,36864,55296,64512,73728,82944,92160,
                          101376,110592,138240,147456};
    const int wcin[11] = {64,64,64,32,32,32,32,32,32,96,32};
    for (int j = (blk-16)*256 + t; j < 147456; j += 64*256) {
      int s = 0;
      #pragma unroll
      for (int q = 1; q <= 10; ++q) s += (j >= csum[q]);
      const int jj = j - csum[s];
      const int cin = wcin[s], K = 9*cin;
      const int co = jj / K, k = jj - co*K;
      const int kk = k / cin, ci = k - kk*cin;
      p.wbf[j] = __float2bfloat16(p.wsrc[s][(size_t)(co*cin + ci)*9 + kk]);
    }
  } else {
    const int b2 = blk - 80;
    const int y = b2 & 63, b = b2 >> 6;
    for (int j = t; j < 4096; j += 256) {
      int ci = j >> 6, xx = j & 63;
      float v = p.x[((size_t)(b*64 + ci)*64 + y)*64 + xx];
      p.xcat[((size_t)b*PIX_P + (size_t)(y+1)*66 + xx+1)*96 + ci] = __float2bfloat16(v);
    }
  }
}

// ---------------------------------------------------------------------------
// MFMA implicit-GEMM 3x3 conv + bias + ReLU. K-split 4-wave blocks (R10).
// mode bit 4 now writes TILED channel-major: [pix/32][c][pix%32] so the
// attention Z-operand loads are contiguous (fixes 8KB-stride L1 set aliasing).
// ---------------------------------------------------------------------------
struct ConvPar {
  const __hip_bfloat16* in[3];
  const __hip_bfloat16* wb[3];
  const float* bias[3];
  __hip_bfloat16* outPad[3];
  __hip_bfloat16* outPix[3];
  __hip_bfloat16* outCh[3];
  float* outF[3];
  int mode, sch;
};

template<int CIN>
__global__ __launch_bounds__(256) void conv_mfma(ConvPar p)
{
  constexpr int K = 9*CIN;
  constexpr int S = K/32;            // total k-steps
  constexpr int Q = S/4, R = S%4;
  constexpr int e0 = Q + (R>0 ? 1:0);
  constexpr int e1 = e0 + Q + (R>1 ? 1:0);
  constexpr int e2 = e1 + Q + (R>2 ? 1:0);
  const int sel = blockIdx.y, b = blockIdx.z;
  const int sch = p.sch;
  const __hip_bfloat16* __restrict__ in = p.in[sel] + (size_t)b*PIX_P*sch;
  const __hip_bfloat16* __restrict__ wb = p.wb[sel];
  const float* __restrict__ bias = p.bias[sel];
  const int t = threadIdx.x, wave = t >> 6, lane = t & 63;
  const int l15 = lane & 15, q4 = lane >> 4;
  const int y = blockIdx.x >> 2;
  const int xw = (blockIdx.x & 3)*16;

  __shared__ float red[3][16][33];

  f32x4 acc0 = {0.f,0.f,0.f,0.f}, acc1 = {0.f,0.f,0.f,0.f};

#define CONV_BODY(ks)                                                          \
  {                                                                            \
    const int kk  = ((ks)*32)/CIN;                                             \
    const int ci0 = ((ks)*32)%CIN + q4*8;                                      \
    const int dy = kk/3 - 1, dx = (kk%3) - 1;                                  \
    const short8 bw0 = *(const short8*)&wb[(size_t)l15*K      + (ks)*32 + q4*8]; \
    const short8 bw1 = *(const short8*)&wb[(size_t)(16+l15)*K + (ks)*32 + q4*8]; \
    const short8 av  = *(const short8*)&in[((size_t)(y+1+dy)*66 + xw + l15 + 1 + dx)*sch + ci0]; \
    acc0 = __builtin_amdgcn_mfma_f32_16x16x32_bf16(av, bw0, acc0, 0, 0, 0);    \
    acc1 = __builtin_amdgcn_mfma_f32_16x16x32_bf16(av, bw1, acc1, 0, 0, 0);    \
  }

  if (wave == 0) {
    #pragma unroll
    for (int ks = 0; ks < e0; ++ks) CONV_BODY(ks)
  } else if (wave == 1) {
    #pragma unroll
    for (int ks = e0; ks < e1; ++ks) CONV_BODY(ks)
  } else if (wave == 2) {
    #pragma unroll
    for (int ks = e1; ks < e2; ++ks) CONV_BODY(ks)
  } else {
    #pragma unroll
    for (int ks = e2; ks < S; ++ks) CONV_BODY(ks)
  }
#undef CONV_BODY

  if (wave > 0) {
    #pragma unroll
    for (int r = 0; r < 4; ++r) {
      red[wave-1][q4*4 + r][l15]      = acc0[r];
      red[wave-1][q4*4 + r][16 + l15] = acc1[r];
    }
  }
  __syncthreads();
  if (wave == 0) {
    const float bz0 = bias[l15], bz1 = bias[16 + l15];
    #pragma unroll
    for (int r = 0; r < 4; ++r) {
      const int px = q4*4 + r;
      const float v0 = fmaxf(acc0[r] + red[0][px][l15] + red[1][px][l15]
                             + red[2][px][l15] + bz0, 0.f);
      const float v1 = fmaxf(acc1[r] + red[0][px][16+l15] + red[1][px][16+l15]
                             + red[2][px][16+l15] + bz1, 0.f);
      const int xx = xw + px;
      const int pix = y*64 + xx;
      if (p.mode & 1) {
        __hip_bfloat16* o = p.outPad[sel] + ((size_t)b*PIX_P + (size_t)(y+1)*66 + xx+1)*32;
        o[l15] = __float2bfloat16(v0); o[16+l15] = __float2bfloat16(v1);
      }
      if (p.mode & 2) {
        __hip_bfloat16* o = p.outPix[sel] + ((size_t)b*N_PIX + pix)*32;
        o[l15] = __float2bfloat16(v0); o[16+l15] = __float2bfloat16(v1);
      }
      if (p.mode & 4) {   // tiled channel-major [pix/32][c][pix%32]
        __hip_bfloat16* o = p.outCh[sel] + (size_t)b*32*N_PIX
                            + (size_t)(pix >> 5)*1024 + (pix & 31);
        o[(size_t)l15*32]      = __float2bfloat16(v0);
        o[(size_t)(16+l15)*32] = __float2bfloat16(v1);
      }
      if (p.mode & 8) {
        float* o = p.outF[sel] + (size_t)b*32*N_PIX + pix;
        o[(size_t)l15*N_PIX]      = v0;
        o[(size_t)(16+l15)*N_PIX] = v1;
      }
    }
  }
}

// ---------------------------------------------------------------------------
// a3avg_k: fused per-pass output conv (wr/wg/wb) + 3-way average, writing
// xcat channels 64..95 directly. Block = 16 px, 3 waves (one per weight set);
// LDS reduce; wave 0 averages and stores. Removes one launch + rgb round-trip.
// ---------------------------------------------------------------------------
struct A3Par {
  const __hip_bfloat16* ctxP;   // slots [pass*BB + b]
  const __hip_bfloat16* wb[3];
  const float* bias[3];
  __hip_bfloat16* xcat;
};

__global__ __launch_bounds__(192) void a3avg_k(A3Par p)
{
  constexpr int K = 288;
  const int t = threadIdx.x, wave = t >> 6, lane = t & 63;
  const int l15 = lane & 15, q4 = lane >> 4;
  const int b = blockIdx.y;
  const int y = blockIdx.x >> 2;
  const int xw = (blockIdx.x & 3)*16;
  const int sel = wave;
  const __hip_bfloat16* __restrict__ in = p.ctxP + ((size_t)(sel*BB + b))*PIX_P*32;
  const __hip_bfloat16* __restrict__ wb = p.wb[sel];
  const float* __restrict__ bias = p.bias[sel];

  __shared__ float red[2][16][33];

  f32x4 acc0 = {0.f,0.f,0.f,0.f}, acc1 = {0.f,0.f,0.f,0.f};
  #pragma unroll
  for (int ks = 0; ks < 9; ++ks) {
    const int dy = ks/3 - 1, dx = (ks%3) - 1;
    const short8 bw0 = *(const short8*)&wb[(size_t)l15*K      + ks*32 + q4*8];
    const short8 bw1 = *(const short8*)&wb[(size_t)(16+l15)*K + ks*32 + q4*8];
    const short8 av  = *(const short8*)&in[((size_t)(y+1+dy)*66 + xw + l15 + 1 + dx)*32 + q4*8];
    acc0 = __builtin_amdgcn_mfma_f32_16x16x32_bf16(av, bw0, acc0, 0, 0, 0);
    acc1 = __builtin_amdgcn_mfma_f32_16x16x32_bf16(av, bw1, acc1, 0, 0, 0);
  }
  const float bz0 = bias[l15], bz1 = bias[16 + l15];
  #pragma unroll
  for (int r = 0; r < 4; ++r) {
    acc0[r] = fmaxf(acc0[r] + bz0, 0.f);
    acc1[r] = fmaxf(acc1[r] + bz1, 0.f);
  }
  if (wave > 0) {
    #pragma unroll
    for (int r = 0; r < 4; ++r) {
      red[wave-1][q4*4 + r][l15]      = acc0[r];
      red[wave-1][q4*4 + r][16 + l15] = acc1[r];
    }
  }
  __syncthreads();
  if (wave == 0) {
    #pragma unroll
    for (int r = 0; r < 4; ++r) {
      const int px = q4*4 + r;
      const float v0 = (acc0[r] + red[0][px][l15]    + red[1][px][l15])    * (1.0f/3.0f);
      const float v1 = (acc1[r] + red[0][px][16+l15] + red[1][px][16+l15]) * (1.0f/3.0f);
      const int xx = xw + px;
      __hip_bfloat16* o = p.xcat + ((size_t)b*PIX_P + (size_t)(y+1)*66 + xx+1)*96 + 64;
      o[l15]      = __float2bfloat16(v0);
      o[16 + l15] = __float2bfloat16(v1);
    }
  }
}

// ---------------------------------------------------------------------------
// Attention pass, 32x32x16 MFMA, in-register P (verified R8-R10).
// Z operand now TILED channel-major: bz addr = (m0+l31)*32 + l5*8 (+16) -
// contiguous 1KB per load, no L1 set aliasing.
// ---------------------------------------------------------------------------
__global__ __launch_bounds__(512, 6) void attn_mfma(
    const __hip_bfloat16* __restrict__ qP, const __hip_bfloat16* __restrict__ kP,
    const __hip_bfloat16* __restrict__ vP,
    const __hip_bfloat16* __restrict__ qT, const __hip_bfloat16* __restrict__ kT,
    const __hip_bfloat16* __restrict__ vT,
    __hip_bfloat16* __restrict__ ctxPad)
{
  const int pass = blockIdx.y, b = blockIdx.z;
  const __hip_bfloat16 *XT, *YT, *ZT;
  if (pass == 0)      { XT = qP; YT = kP; ZT = vT; }
  else if (pass == 1) { XT = kP; YT = vP; ZT = qT; }
  else                { XT = vP; YT = qP; ZT = kT; }
  const size_t boff = (size_t)b * CCH * N_PIX;
  XT += boff; YT += boff; ZT += boff;
  __hip_bfloat16* __restrict__ ctx = ctxPad + ((size_t)(pass*BB + b))*PIX_P*32;

  const int t = threadIdx.x;
  const int wave = t >> 6, lane = t & 63;
  const int l31 = lane & 31, l5 = lane >> 5;
  const int n0 = blockIdx.x * 32;
  const int mbase = wave * (N_PIX/8);

  __shared__ float mgO[7][16][64];   // waves 1..7 partial O
  __shared__ float mgD[8][32];       // per-wave denominators by query i

  // GEMM1 B-frag (X): col = i = lane&31, k = c = l5*8 + e (two K=16 halves)
  const short8 bx0 = *(const short8*)&XT[(size_t)(n0 + l31)*CCH + l5*8];
  const short8 bx1 = *(const short8*)&XT[(size_t)(n0 + l31)*CCH + 16 + l5*8];

  f32x16 oacc = {0,0,0,0,0,0,0,0,0,0,0,0,0,0,0,0};
  float rs0 = 0.f, rs1 = 0.f, rs2 = 0.f, rs3 = 0.f;
  const float SC2 = 0.17677669529663687f * 1.4426950408889634f;  // 32^-0.5 * log2(e)
  const float OFF = 20.0f;

  #pragma unroll 2
  for (int m0 = mbase; m0 < mbase + N_PIX/8; m0 += 32) {
    // GEMM1: A = Y rows (m = lane&31)
    const short8 ay0 = *(const short8*)&YT[(size_t)(m0 + l31)*CCH + l5*8];
    const short8 ay1 = *(const short8*)&YT[(size_t)(m0 + l31)*CCH + 16 + l5*8];
    f32x16 s = {0,0,0,0,0,0,0,0,0,0,0,0,0,0,0,0};
    s = __builtin_amdgcn_mfma_f32_32x32x16_bf16(ay0, bx0, s, 0, 0, 0);
    s = __builtin_amdgcn_mfma_f32_32x32x16_bf16(ay1, bx1, s, 0, 0, 0);

    // P = 2^(s*SC2 - OFF) via bare v_exp_f32 (args bounded; no range fixup)
    float p[16];
    #pragma unroll
    for (int r = 0; r < 16; ++r) {
      const float arg = fmaf(s[r], SC2, -OFF);
      asm("v_exp_f32 %0, %1" : "=v"(p[r]) : "v"(arg));
    }
    #pragma unroll
    for (int r = 0; r < 4; ++r) {
      rs0 += p[r];
      rs1 += p[4 + r];
      rs2 += p[8 + r];
      rs3 += p[12 + r];
    }

    // pack to bf16 pairs: w[rhi*2+j] = {m = 8*rhi + 4*l5 + 2j, +1}
    unsigned w[8];
    #pragma unroll
    for (int h = 0; h < 8; ++h) {
      const int rhi = h >> 1, j = h & 1;
      asm("v_cvt_pk_bf16_f32 %0, %1, %2"
          : "=v"(w[h]) : "v"(p[rhi*4 + 2*j]), "v"(p[rhi*4 + 2*j + 1]));
    }
    // lane<->lane+32 exchange -> GEMM2 A-fragments in-register
    asm("v_permlane32_swap_b32 %0, %1" : "+v"(w[2]), "+v"(w[0]));
    asm("v_permlane32_swap_b32 %0, %1" : "+v"(w[3]), "+v"(w[1]));
    asm("v_permlane32_swap_b32 %0, %1" : "+v"(w[6]), "+v"(w[4]));
    asm("v_permlane32_swap_b32 %0, %1" : "+v"(w[7]), "+v"(w[5]));
    union U { unsigned u[4]; short8 v8; };
    U A0, A1;
    A0.u[0] = w[0]; A0.u[1] = w[1]; A0.u[2] = w[2]; A0.u[3] = w[3];
    A1.u[0] = w[4]; A1.u[1] = w[5]; A1.u[2] = w[6]; A1.u[3] = w[7];

    // GEMM2: B = Z cols from TILED channel-major (contiguous 1KB per load)
    const short8 bz0 = *(const short8*)&ZT[(size_t)(m0 + l31)*32 + l5*8];
    const short8 bz1 = *(const short8*)&ZT[(size_t)(m0 + l31)*32 + 16 + l5*8];
    oacc = __builtin_amdgcn_mfma_f32_32x32x16_bf16(A0.v8, bz0, oacc, 0, 0, 0);
    oacc = __builtin_amdgcn_mfma_f32_32x32x16_bf16(A1.v8, bz1, oacc, 0, 0, 0);
  }

  // denominator: combine partials + l5 halves -> full sum for query i
  float rs = (rs0 + rs1) + (rs2 + rs3);
  rs += __shfl_xor(rs, 32);
  if (l5 == 0) mgD[wave][l31] = rs;
  if (wave) {
    #pragma unroll
    for (int r = 0; r < 16; ++r) mgO[wave-1][r][lane] = oacc[r];
  }
  __syncthreads();
  if (wave == 0) {
    #pragma unroll
    for (int r = 0; r < 16; ++r) {
      const int i = (r & 3) + 8*(r >> 2) + 4*l5;
      float den = 0.f, tot = oacc[r];
      #pragma unroll
      for (int ww = 0; ww < 8; ++ww) den += mgD[ww][i];
      #pragma unroll
      for (int ww = 0; ww < 7; ++ww) tot += mgO[ww][r][lane];
      const int pix = n0 + i;
      const int yy = pix >> 6, xx = pix & 63;
      ctx[((size_t)(yy+1)*66 + xx+1)*32 + l31] = __float2bfloat16(tot / den);
    }
  }
}

// ---------------------------------------------------------------------------
extern "C" void kernel_launch(void* const* d_in, const int* in_sizes, int n_in,
                              void* d_out, int out_size, void* d_ws, size_t ws_size,
                              hipStream_t stream)
{
  const float* x   = (const float*)d_in[0];
  const float* wq1 = (const float*)d_in[1];  const float* bq1 = (const float*)d_in[2];
  const float* wq2 = (const float*)d_in[3];  const float* bq2 = (const float*)d_in[4];
  const float* wk1 = (const float*)d_in[5];  const float* bk1 = (const float*)d_in[6];
  const float* wk2 = (const float*)d_in[7];  const float* bk2 = (const float*)d_in[8];
  const float* wv1 = (const float*)d_in[9];  const float* bv1 = (const float*)d_in[10];
  const float* wv2 = (const float*)d_in[11]; const float* bv2 = (const float*)d_in[12];
  const float* wr  = (const float*)d_in[13]; const float* br  = (const float*)d_in[14];
  const float* wg  = (const float*)d_in[15]; const float* bg  = (const float*)d_in[16];
  const float* wb_ = (const float*)d_in[17]; const float* bb_ = (const float*)d_in[18];
  const float* w2  = (const float*)d_in[19]; const float* b2  = (const float*)d_in[20];
  const float* w3  = (const float*)d_in[21]; const float* b3  = (const float*)d_in[22];

  // ---- workspace layout (bytes) ----
  char* base = (char*)d_ws;
  __hip_bfloat16* xcat  = (__hip_bfloat16*)(base + 0);        // [2][4356][96] padded
  __hip_bfloat16* q1p   = (__hip_bfloat16*)(base + 1672704);  // [3][2][4356][32] padded
  __hip_bfloat16* ctxP  = (__hip_bfloat16*)(base + 3345408);  // [3][2][4356][32] padded
  __hip_bfloat16* out4p = (__hip_bfloat16*)(base + 5018112);  // [2][4356][32] padded
  __hip_bfloat16* qkvP  = (__hip_bfloat16*)(base + 5575680);  // [3][2][4096][32]
  __hip_bfloat16* qkvT  = (__hip_bfloat16*)(base + 7148544);  // [3][2][128][32][32] tiled
  __hip_bfloat16* wbf   = (__hip_bfloat16*)(base + 8721408);  // 147456 elems
  const size_t PADSLOT = (size_t)BB*PIX_P*32;
  const size_t UPSLOT  = (size_t)BB*N_PIX*32;

  // prep: border zeros + weight cvt + x padding in ONE launch
  PrepPar pp;
  for (int i = 0; i < 2; ++i)  { pp.bz[i]    = xcat  + (size_t)i*PIX_P*96; pp.bzsch[i]    = 96; }
  for (int i = 0; i < 6; ++i)  { pp.bz[2+i]  = q1p   + (size_t)i*PIX_P*32; pp.bzsch[2+i]  = 32; }
  for (int i = 0; i < 6; ++i)  { pp.bz[8+i]  = ctxP  + (size_t)i*PIX_P*32; pp.bzsch[8+i]  = 32; }
  for (int i = 0; i < 2; ++i)  { pp.bz[14+i] = out4p + (size_t)i*PIX_P*32; pp.bzsch[14+i] = 32; }
  const float* wsrc[11] = {wq1,wk1,wv1,wq2,wk2,wv2,wr,wg,wb_,w2,w3};
  for (int i = 0; i < 11; ++i) pp.wsrc[i] = wsrc[i];
  pp.x = x; pp.xcat = xcat; pp.wbf = wbf;
  prep_k<<<dim3(208), dim3(256), 0, stream>>>(pp);

  // a1: xcat(ch 0..63) -> q1p/k1p/v1p (padded bf16)
  ConvPar c1 = {};
  for (int i = 0; i < 3; ++i) c1.in[i] = xcat;
  c1.wb[0]=wbf+0; c1.wb[1]=wbf+18432; c1.wb[2]=wbf+36864;
  c1.bias[0]=bq1; c1.bias[1]=bk1; c1.bias[2]=bv1;
  c1.outPad[0]=q1p; c1.outPad[1]=q1p+PADSLOT; c1.outPad[2]=q1p+2*PADSLOT;
  c1.mode = 1; c1.sch = 96;
  conv_mfma<64><<<dim3(256, 3, BB), dim3(256), 0, stream>>>(c1);

  // a2: q1p -> q/k/v in pixel-major + tiled channel-major
  ConvPar c2 = {};
  c2.in[0]=q1p; c2.in[1]=q1p+PADSLOT; c2.in[2]=q1p+2*PADSLOT;
  c2.wb[0]=wbf+55296; c2.wb[1]=wbf+64512; c2.wb[2]=wbf+73728;
  c2.bias[0]=bq2; c2.bias[1]=bk2; c2.bias[2]=bv2;
  c2.outPix[0]=qkvP; c2.outPix[1]=qkvP+UPSLOT; c2.outPix[2]=qkvP+2*UPSLOT;
  c2.outCh[0]=qkvT;  c2.outCh[1]=qkvT+UPSLOT;  c2.outCh[2]=qkvT+2*UPSLOT;
  c2.mode = 6; c2.sch = 32;
  conv_mfma<32><<<dim3(256, 3, BB), dim3(256), 0, stream>>>(c2);

  // attention: 3 passes x 2 batches -> ctxP (padded bf16)
  attn_mfma<<<dim3(N_PIX/32, 3, BB), dim3(512), 0, stream>>>(
      qkvP, qkvP+UPSLOT, qkvP+2*UPSLOT, qkvT, qkvT+UPSLOT, qkvT+2*UPSLOT, ctxP);

  // a3+avg fused: ctxP -> conv_r/g/b -> average -> xcat channels 64..95
  A3Par a3;
  a3.ctxP = ctxP;
  a3.wb[0]=wbf+82944; a3.wb[1]=wbf+92160; a3.wb[2]=wbf+101376;
  a3.bias[0]=br; a3.bias[1]=bg; a3.bias[2]=bb_;
  a3.xcat = xcat;
  a3avg_k<<<dim3(256, BB), dim3(192), 0, stream>>>(a3);

  // a4: xcat (96 ch) -> out4p (padded bf16)
  ConvPar c4 = {};
  c4.in[0]=xcat; c4.wb[0]=wbf+110592; c4.bias[0]=b2;
  c4.outPad[0]=out4p; c4.mode = 1; c4.sch = 96;
  conv_mfma<96><<<dim3(256, 1, BB), dim3(256), 0, stream>>>(c4);

  // a5: out4p -> d_out (fp32 NCHW)
  ConvPar c5 = {};
  c5.in[0]=out4p; c5.wb[0]=wbf+138240; c5.bias[0]=b3;
  c5.outF[0]=(float*)d_out; c5.mode = 8; c5.sch = 32;
  conv_mfma<32><<<dim3(256, 1, BB), dim3(256), 0, stream>>>(c5);
}